// Round 17
// baseline (1238.612 us; speedup 1.0000x reference)
//
#include <hip/hip_runtime.h>
#include <math.h>

// Residual VQ: x (262144,128) fp32, codebooks (3,256,128) fp32.
// Output: [indices as float (262144*3)] ++ [quantized (262144*128)].
//
// ARITHMETIC CONTRACT (absmax=0 — do not change):
//   M_k  = OpenBLAS sgemm K-loop: sequential FMA chain j=0..127, acc init 0
//   A    = np.sum(r*r): pairwise_sum 8-accumulator scheme, products rounded
//          separately (fmaf(x,x,0) = single-rounded product, blocks fusion)
//   d2_k = (A - 2.0f*M_k) + B_k ; argmin strict < ascending k == first-min
//          (per-lane v-ascending strict-<, then (val,idx) shuffle-reduce
//           with tie -> smaller idx: identical semantics)
//   residual: r1 = x - q0, r2 = r1 - q1 — in-place global scratch, ref order
//   quantized = (q0 + q1) + q2 elementwise fp32, ref order
//
// ROUND 21 CHANGE: r20's register-tile broke the 1.2ms plateau (1150us,
// FETCH 152MB, WRITE 372MB ~= ideal, VGPR 108 clean) but VALUBusy 40%:
// every phase's FIRST FMA consumes ALL 16 codebook regs, so each of the 32
// phases exposes a full L2 load latency (~300cyc) before its 512cyc FMA
// block — at 2 waves/SIMD that's ~40-55% duty, as measured. Fix: classic
// GEMM double-buffer. Two 16-reg sets u/v, phase loop unrolled x2 ping-pong:
// phase p computes on u while phase p+1's loads fill v (no movs, +16 VGPR ->
// ~124, inside the bound-2 cap 128). Per-phase exposure -> ~0 (loads get 512
// FMA-cycles to land). Residual broadcast loads already pipeline across the
// 16 items. Prefetch changes timing only — same loads, same chains, same
// rounding (r20 verified absmax=0).

constexpr int kItems = 262144;
constexpr int kDim   = 128;
constexpr int kNcb   = 3;
constexpr int kK     = 256;
constexpr int kBlock = 256;
constexpr int kBatch = 16;        // items per wave (wave-private batch)
constexpr int NPH    = 32;        // phases of 4 dims

__device__ __forceinline__ float sq_rn(float x) {
    return __builtin_fmaf(x, x, 0.0f);
}

// numpy pairwise_sum, n=128 (for the B-table)
template <typename F>
__device__ __forceinline__ float np_pairwise128(F term) {
    float r0 = term(0), r1 = term(1), r2 = term(2), r3 = term(3),
          r4 = term(4), r5 = term(5), r6 = term(6), r7 = term(7);
    #pragma unroll
    for (int i = 8; i < 128; i += 8) {
        r0 = r0 + term(i + 0); r1 = r1 + term(i + 1);
        r2 = r2 + term(i + 2); r3 = r3 + term(i + 3);
        r4 = r4 + term(i + 4); r5 = r5 + term(i + 5);
        r6 = r6 + term(i + 6); r7 = r7 + term(i + 7);
    }
    return ((r0 + r1) + (r2 + r3)) + ((r4 + r5) + (r6 + r7));
}

// ---------- pre-kernel: Bt (768 floats) + transposed codebook cbT:
// cbT[(c*128 + j)*256 + e] = cb[(c*256 + e)*128 + j]
__global__ void rvq_prep(const float* __restrict__ cb,
                         float* __restrict__ Bt,
                         float* __restrict__ cbT)
{
    const int tid = blockIdx.x * 256 + threadIdx.x;   // 384*256 = 98304
    const int e = tid & 255;
    const int j = (tid >> 8) & 127;
    const int c = tid >> 15;
    cbT[tid] = cb[((size_t)c * kK + e) * kDim + j];
    if (tid < kNcb * kK) {
        const float* row = cb + (size_t)tid * kDim;
        Bt[tid] = np_pairwise128([&](int jj) { return sq_rn(row[jj]); });
    }
}

#define X16(X) X(0) X(1) X(2) X(3) X(4) X(5) X(6) X(7) \
  X(8) X(9) X(10) X(11) X(12) X(13) X(14) X(15)

#define MDECL(i) float m##i##_0 = 0.f, m##i##_1 = 0.f, \
                       m##i##_2 = 0.f, m##i##_3 = 0.f;

// declare one 16-reg codebook tile set with prefix R
#define CBSET(R) float R##0_0, R##0_1, R##0_2, R##0_3, \
                       R##1_0, R##1_1, R##1_2, R##1_3, \
                       R##2_0, R##2_1, R##2_2, R##2_3, \
                       R##3_0, R##3_1, R##3_2, R##3_3;

// load phase PH's 16 transposed-codebook values into set R (per-lane dwords)
#define CBLOAD(R, PH) { \
    const float* cbp_ = cbTc + (size_t)(4 * (PH)) * kK + lane; \
    R##0_0 = cbp_[0];   R##0_1 = cbp_[64];  R##0_2 = cbp_[128]; R##0_3 = cbp_[192]; \
    R##1_0 = cbp_[256]; R##1_1 = cbp_[320]; R##1_2 = cbp_[384]; R##1_3 = cbp_[448]; \
    R##2_0 = cbp_[512]; R##2_1 = cbp_[576]; R##2_2 = cbp_[640]; R##2_3 = cbp_[704]; \
    R##3_0 = cbp_[768]; R##3_1 = cbp_[832]; R##3_2 = cbp_[896]; R##3_3 = cbp_[960]; }

// one item's phase step on tile set R at phase P: broadcast residual float4
// (same addr all lanes), 16 FMAs; per-acc chain = d ascending within phase,
// phases ascending -> j = 0..127 sequential (OpenBLAS K order, bit-exact)
#define MITEM(i, R, P) { \
    const float4 rv = *(const float4*)(rb_ + (size_t)(i) * kDim + 4 * (P)); \
    m##i##_0 = __builtin_fmaf(rv.x, R##0_0, m##i##_0); \
    m##i##_0 = __builtin_fmaf(rv.y, R##1_0, m##i##_0); \
    m##i##_0 = __builtin_fmaf(rv.z, R##2_0, m##i##_0); \
    m##i##_0 = __builtin_fmaf(rv.w, R##3_0, m##i##_0); \
    m##i##_1 = __builtin_fmaf(rv.x, R##0_1, m##i##_1); \
    m##i##_1 = __builtin_fmaf(rv.y, R##1_1, m##i##_1); \
    m##i##_1 = __builtin_fmaf(rv.z, R##2_1, m##i##_1); \
    m##i##_1 = __builtin_fmaf(rv.w, R##3_1, m##i##_1); \
    m##i##_2 = __builtin_fmaf(rv.x, R##0_2, m##i##_2); \
    m##i##_2 = __builtin_fmaf(rv.y, R##1_2, m##i##_2); \
    m##i##_2 = __builtin_fmaf(rv.z, R##2_2, m##i##_2); \
    m##i##_2 = __builtin_fmaf(rv.w, R##3_2, m##i##_2); \
    m##i##_3 = __builtin_fmaf(rv.x, R##0_3, m##i##_3); \
    m##i##_3 = __builtin_fmaf(rv.y, R##1_3, m##i##_3); \
    m##i##_3 = __builtin_fmaf(rv.z, R##2_3, m##i##_3); \
    m##i##_3 = __builtin_fmaf(rv.w, R##3_3, m##i##_3); }

#define MITEMS_U(P) \
    MITEM(0,u,P) MITEM(1,u,P) MITEM(2,u,P) MITEM(3,u,P) \
    MITEM(4,u,P) MITEM(5,u,P) MITEM(6,u,P) MITEM(7,u,P) \
    MITEM(8,u,P) MITEM(9,u,P) MITEM(10,u,P) MITEM(11,u,P) \
    MITEM(12,u,P) MITEM(13,u,P) MITEM(14,u,P) MITEM(15,u,P)
#define MITEMS_V(P) \
    MITEM(0,v,P) MITEM(1,v,P) MITEM(2,v,P) MITEM(3,v,P) \
    MITEM(4,v,P) MITEM(5,v,P) MITEM(6,v,P) MITEM(7,v,P) \
    MITEM(8,v,P) MITEM(9,v,P) MITEM(10,v,P) MITEM(11,v,P) \
    MITEM(12,v,P) MITEM(13,v,P) MITEM(14,v,P) MITEM(15,v,P)

// d2 + argmin for item i (strict <, v ascending, then butterfly; tie ->
// smaller idx == numpy first-min over all 256 entries)
#define ARGMIN(i) { \
    const float Ai = __shfl(Areg, (i)); \
    float bv = __builtin_fmaf(-2.0f, m##i##_0, Ai) + B0; \
    int   bx = lane; \
    float dd = __builtin_fmaf(-2.0f, m##i##_1, Ai) + B1; \
    if (dd < bv) { bv = dd; bx = 64 + lane; } \
    dd = __builtin_fmaf(-2.0f, m##i##_2, Ai) + B2; \
    if (dd < bv) { bv = dd; bx = 128 + lane; } \
    dd = __builtin_fmaf(-2.0f, m##i##_3, Ai) + B3; \
    if (dd < bv) { bv = dd; bx = 192 + lane; } \
    _Pragma("unroll") \
    for (int off = 32; off; off >>= 1) { \
        const float ov = __shfl_xor(bv, off); \
        const int   ox = __shfl_xor(bx, off); \
        const bool take = (ov < bv) || (ov == bv && ox < bx); \
        bv = take ? ov : bv; bx = take ? ox : bx; \
    } \
    if (c == 0)      sel0 = (lane == (i)) ? bx : sel0; \
    else if (c == 1) sel1 = (lane == (i)) ? bx : sel1; \
    else             sel2 = (lane == (i)) ? bx : sel2; }

__global__ __launch_bounds__(kBlock, 2) void rvq_kernel(
    const float* __restrict__ x,
    const float* __restrict__ cb,
    const float* __restrict__ Bt,
    const float* __restrict__ cbT,
    float* __restrict__ out)
{
    const int t = threadIdx.x;
    const int lane = t & 63;
    // global wave id = batch id; each wave fully independent (no LDS, no bar)
    const int wid = blockIdx.x * (kBlock / 64) + (t >> 6);
    const size_t ibase = (size_t)wid * kBatch;

    float* out_idx = out;                             // (items, 3) as float
    float* out_q   = out + (size_t)kItems * kNcb;     // (items, 128)

    const float* xb = x + ibase * kDim;               // batch x rows
    float*       qb = out_q + ibase * kDim;           // batch scratch rows

    int sel0 = 0, sel1 = 0, sel2 = 0;                 // lane i: item i's sel

    #pragma unroll 1
    for (int c = 0; c < kNcb; ++c) {
        const float* rb_ = (c == 0) ? xb : (const float*)qb;
        const float* cbTc = cbT + (size_t)c * kDim * kK;

        // ---- A: lane i computes item i's np.sum(r*r), 8-stripe pairwise
        float Areg = 0.0f;
        if (lane < kBatch) {
            const float4* rr = (const float4*)(rb_ + (size_t)lane * kDim);
            float4 ra = rr[0], rb2 = rr[1];
            float a0 = sq_rn(ra.x),  a1 = sq_rn(ra.y),
                  a2 = sq_rn(ra.z),  a3 = sq_rn(ra.w),
                  a4 = sq_rn(rb2.x), a5 = sq_rn(rb2.y),
                  a6 = sq_rn(rb2.z), a7 = sq_rn(rb2.w);
            #pragma unroll
            for (int g = 1; g < 16; ++g) {
                ra = rr[2 * g]; rb2 = rr[2 * g + 1];
                a0 = a0 + sq_rn(ra.x);  a1 = a1 + sq_rn(ra.y);
                a2 = a2 + sq_rn(ra.z);  a3 = a3 + sq_rn(ra.w);
                a4 = a4 + sq_rn(rb2.x); a5 = a5 + sq_rn(rb2.y);
                a6 = a6 + sq_rn(rb2.z); a7 = a7 + sq_rn(rb2.w);
            }
            Areg = ((a0 + a1) + (a2 + a3)) + ((a4 + a5) + (a6 + a7));
        }

        // ---- M: 64 accs (16 items x 4 entry-groups); codebook tile
        // double-buffered in registers (u/v ping-pong, no movs)
        X16(MDECL)
        CBSET(u)
        CBSET(v)
        CBLOAD(u, 0)
        #pragma unroll 1
        for (int pp = 0; pp < NPH / 2 - 1; ++pp) {      // phases 0..29
            CBLOAD(v, 2 * pp + 1)                       // prefetch odd phase
            MITEMS_U(2 * pp)                            // compute even phase
            CBLOAD(u, 2 * pp + 2)                       // prefetch next even
            MITEMS_V(2 * pp + 1)                        // compute odd phase
        }
        CBLOAD(v, NPH - 1)                              // phase 31
        MITEMS_U(NPH - 2)                               // phase 30
        MITEMS_V(NPH - 1)                               // phase 31

        // ---- argmin (B per-lane, coalesced)
        const float* Btc = Bt + c * kK;
        const float B0 = Btc[lane],       B1 = Btc[64 + lane];
        const float B2 = Btc[128 + lane], B3 = Btc[192 + lane];
        X16(ARGMIN)

        // ---- residual update into wave-private scratch rows
        if (c < 2) {
            #pragma unroll 1
            for (int i = 0; i < kBatch; ++i) {
                const int s = __shfl((c == 0) ? sel0 : sel1, i);
                const float* cwrow = cb + ((size_t)c * kK + s) * kDim;
                const float2 w = *(const float2*)(cwrow + 2 * lane);
                float* dr = qb + (size_t)i * kDim;
                const float* sr = (c == 0) ? (xb + (size_t)i * kDim)
                                           : (const float*)dr;
                float2 rv = *(const float2*)(sr + 2 * lane);
                rv.x = rv.x - w.x;             // one rounding each, ref order
                rv.y = rv.y - w.y;
                *(float2*)(dr + 2 * lane) = rv;
            }
            // scratch writes must be visible to this wave's next-cb loads
            asm volatile("s_waitcnt vmcnt(0)" ::: "memory");
        }
    }

    // ---- outputs: quantized (overwrites scratch; all r2 reads done) + idx
    #pragma unroll 1
    for (int i = 0; i < kBatch; ++i) {
        const int s0 = __shfl(sel0, i);
        const int s1 = __shfl(sel1, i);
        const int s2 = __shfl(sel2, i);
        const float2 u = *(const float2*)(cb + ((size_t)0 * kK + s0) * kDim + 2 * lane);
        const float2 v = *(const float2*)(cb + ((size_t)1 * kK + s1) * kDim + 2 * lane);
        const float2 w = *(const float2*)(cb + ((size_t)2 * kK + s2) * kDim + 2 * lane);
        float2 o;
        o.x = (u.x + v.x) + w.x;               // ((0+q0)+q1)+q2, ref order
        o.y = (u.y + v.y) + w.y;
        *(float2*)(qb + (size_t)i * kDim + 2 * lane) = o;
        if (lane == 0) {
            out_idx[(ibase + i) * kNcb + 0] = (float)s0;
            out_idx[(ibase + i) * kNcb + 1] = (float)s1;
            out_idx[(ibase + i) * kNcb + 2] = (float)s2;
        }
    }
}

extern "C" void kernel_launch(void* const* d_in, const int* in_sizes, int n_in,
                              void* d_out, int out_size, void* d_ws, size_t ws_size,
                              hipStream_t stream) {
    const float* x  = (const float*)d_in[0];
    const float* cb = (const float*)d_in[1];
    float* out = (float*)d_out;
    float* Bt  = (float*)d_ws;                 // 768 floats
    float* cbT = (float*)d_ws + 1024;          // 98304 floats (384 KB)
    rvq_prep<<<384, 256, 0, stream>>>(cb, Bt, cbT);
    // 16384 waves (one 16-item batch each) = 4096 blocks x 4 waves
    rvq_kernel<<<kItems / (kBatch * 4), kBlock, 0, stream>>>(x, cb, Bt, cbT, out);
}